// Round 2
// baseline (8171.821 us; speedup 1.0000x reference)
//
#include <hip/hip_runtime.h>
#include <hip/hip_bf16.h>
#include <cmath>
#include <cstddef>

// Problem constants (from reference)
#define NN 100000
#define HH 128
#define EE 1600000
#define NH (NN * HH)
#define ALPHA_C 0.1f
#define THETA_C 0.5f
#define EPS_C 1e-5f

constexpr int TR = 64;    // rows per GEMM block
constexpr int AST = 66;   // LDS A-tile stride (floats): 2-way max conflict, float2-aligned

// ---------------------------------------------------------------------------
// Zero kernel (replaces hipMemsetAsync -> no graph-capture risk)
__global__ __launch_bounds__(256) void zero_k(float4* __restrict__ p, int n4) {
    int i = blockIdx.x * 256 + threadIdx.x;
    if (i < n4) p[i] = float4{0.f, 0.f, 0.f, 0.f};
}

// ---------------------------------------------------------------------------
// Index dtype detection: reference casts indices to int64, harness doc says
// int32. If int64 (values < 2^31), every odd 32-bit word is 0; for genuine
// int32 node ids uniform in [0,1e5), 64 consecutive odd words all-zero is
// impossible.
__global__ void detect_idx64(const int* __restrict__ p, int* __restrict__ flag) {
    int any = 0;
    for (int i = 0; i < 64; ++i) any |= p[2 * i + 1];
    *flag = (any == 0) ? 1 : 0;
}

// ---------------------------------------------------------------------------
// Edge scatter with optional fused BN+ReLU on the gathered value:
//   v = z[src[e]][c];  if (scale) v = max(0, v*scale[c]+shift[c]);
//   msg[dst[e]][c] += v
// One wave per edge, float2 per lane (coalesced 512B rows).
__global__ __launch_bounds__(256) void scatter_add_k(
    const float* __restrict__ z, const void* __restrict__ srcp,
    const void* __restrict__ dstp, const int* __restrict__ flag,
    const float* __restrict__ scale, const float* __restrict__ shift,
    float* __restrict__ msg)
{
    int e = blockIdx.x * 4 + (threadIdx.x >> 6);
    int lane = threadIdx.x & 63;
    int s, d;
    if (*flag) {
        s = (int)((const long long*)srcp)[e];
        d = (int)((const long long*)dstp)[e];
    } else {
        s = ((const int*)srcp)[e];
        d = ((const int*)dstp)[e];
    }
    float2 v = ((const float2*)(z + (size_t)s * HH))[lane];
    if (scale) {
        int c = lane * 2;
        v.x = fmaxf(0.f, v.x * scale[c] + shift[c]);
        v.y = fmaxf(0.f, v.y * scale[c + 1] + shift[c + 1]);
    }
    float* mp = msg + (size_t)d * HH + lane * 2;
    atomicAdd(mp, v.x);
    atomicAdd(mp + 1, v.y);
}

// ---------------------------------------------------------------------------
// Generic 128-col GEMM block with fused GCNII epilogue.
//   A_eff[r][k] = cA*src0[r][k] + cB*src1[r][k]   (h = 0.9*msg + 0.1*x0)
//   out[r][c]   = wl*A_eff[r][c] + wm*(A_eff @ W)[r][c] + bias[c]
__global__ __launch_bounds__(256) void gemm128(
    const float* __restrict__ src0, const float* __restrict__ src1,
    float cA, float cB,
    const float* __restrict__ W, const float* __restrict__ bias,
    float wl, float wm, float* __restrict__ out, int nrows)
{
    __shared__ float As[HH * AST];   // A^T tile: [k][row], 128 x 66 -> 33.8 KB
    __shared__ float Ws[32 * HH];    // W chunk:  [k][c],    32 x 128 -> 16 KB

    const int t = threadIdx.x;
    const int tx = t & 31;           // cols 4*tx .. 4*tx+3
    const int ty = t >> 5;           // rows 8*ty .. 8*ty+7
    const int row0 = blockIdx.x * TR;

    const bool useB = (cB != 0.f);
    for (int idx = t; idx < TR * HH; idx += 256) {
        int r = idx >> 7;
        int k = idx & 127;
        float v = 0.f;
        if (row0 + r < nrows) {
            size_t g = (size_t)(row0 + r) * HH + k;
            v = cA * src0[g];
            if (useB) v += cB * src1[g];
        }
        As[k * AST + r] = v;
    }

    float acc[8][4];
#pragma unroll
    for (int i = 0; i < 8; ++i)
#pragma unroll
        for (int j = 0; j < 4; ++j) acc[i][j] = 0.f;

    for (int kc = 0; kc < 4; ++kc) {
        __syncthreads();   // As staged (kc=0) / previous chunk's reads done
        for (int idx = t; idx < 32 * HH; idx += 256) {
            int k = idx >> 7, c = idx & 127;
            Ws[idx] = W[(size_t)(kc * 32 + k) * HH + c];
        }
        __syncthreads();
#pragma unroll
        for (int k = 0; k < 32; ++k) {
            const float* ap = &As[(kc * 32 + k) * AST + ty * 8];
            float2 a01 = *(const float2*)(ap);
            float2 a23 = *(const float2*)(ap + 2);
            float2 a45 = *(const float2*)(ap + 4);
            float2 a67 = *(const float2*)(ap + 6);
            float4 w = *(const float4*)(&Ws[k * HH + tx * 4]);
            float a[8] = {a01.x, a01.y, a23.x, a23.y, a45.x, a45.y, a67.x, a67.y};
#pragma unroll
            for (int i = 0; i < 8; ++i) {
                acc[i][0] += a[i] * w.x;
                acc[i][1] += a[i] * w.y;
                acc[i][2] += a[i] * w.z;
                acc[i][3] += a[i] * w.w;
            }
        }
    }

    float b0 = 0.f, b1 = 0.f, b2 = 0.f, b3 = 0.f;
    if (bias) {
        b0 = bias[tx * 4 + 0]; b1 = bias[tx * 4 + 1];
        b2 = bias[tx * 4 + 2]; b3 = bias[tx * 4 + 3];
    }
#pragma unroll
    for (int i = 0; i < 8; ++i) {
        int rl = ty * 8 + i;
        int r = row0 + rl;
        if (r < nrows) {
            float4 v;
            v.x = wl * As[(tx * 4 + 0) * AST + rl] + wm * acc[i][0] + b0;
            v.y = wl * As[(tx * 4 + 1) * AST + rl] + wm * acc[i][1] + b1;
            v.z = wl * As[(tx * 4 + 2) * AST + rl] + wm * acc[i][2] + b2;
            v.w = wl * As[(tx * 4 + 3) * AST + rl] + wm * acc[i][3] + b3;
            ((float4*)out)[(size_t)r * 32 + tx] = v;
        }
    }
}

// ---------------------------------------------------------------------------
// JumpingKnowledge GEMM: out = concat(z0..z3)[N,512] @ Wjk[512,128] + bjk
// NOTE: out may alias z0 (block reads its z0 rows before writing them).
__global__ __launch_bounds__(256) void gemm_jk(
    const float* __restrict__ z0, const float* __restrict__ z1,
    const float* __restrict__ z2, const float* __restrict__ z3,
    const float* __restrict__ Wjk, const float* __restrict__ bjk,
    float* __restrict__ out, int nrows)
{
    __shared__ float As[HH * AST];
    __shared__ float Ws[32 * HH];

    const int t = threadIdx.x;
    const int tx = t & 31;
    const int ty = t >> 5;
    const int row0 = blockIdx.x * TR;

    float acc[8][4];
#pragma unroll
    for (int i = 0; i < 8; ++i)
#pragma unroll
        for (int j = 0; j < 4; ++j) acc[i][j] = 0.f;

    const float* srcs[4] = {z0, z1, z2, z3};
    for (int j = 0; j < 4; ++j) {
        __syncthreads();   // previous source's As reads done
        const float* Z = srcs[j];
        for (int idx = t; idx < TR * HH; idx += 256) {
            int r = idx >> 7;
            int k = idx & 127;
            float v = 0.f;
            if (row0 + r < nrows) v = Z[(size_t)(row0 + r) * HH + k];
            As[k * AST + r] = v;
        }
        for (int kc = 0; kc < 4; ++kc) {
            __syncthreads();
            for (int idx = t; idx < 32 * HH; idx += 256) {
                int k = idx >> 7, c = idx & 127;
                Ws[idx] = Wjk[(size_t)(j * 128 + kc * 32 + k) * HH + c];
            }
            __syncthreads();
#pragma unroll
            for (int k = 0; k < 32; ++k) {
                const float* ap = &As[(kc * 32 + k) * AST + ty * 8];
                float2 a01 = *(const float2*)(ap);
                float2 a23 = *(const float2*)(ap + 2);
                float2 a45 = *(const float2*)(ap + 4);
                float2 a67 = *(const float2*)(ap + 6);
                float4 w = *(const float4*)(&Ws[k * HH + tx * 4]);
                float a[8] = {a01.x, a01.y, a23.x, a23.y, a45.x, a45.y, a67.x, a67.y};
#pragma unroll
                for (int i = 0; i < 8; ++i) {
                    acc[i][0] += a[i] * w.x;
                    acc[i][1] += a[i] * w.y;
                    acc[i][2] += a[i] * w.z;
                    acc[i][3] += a[i] * w.w;
                }
            }
        }
    }

    float b0 = bjk[tx * 4 + 0], b1 = bjk[tx * 4 + 1];
    float b2 = bjk[tx * 4 + 2], b3 = bjk[tx * 4 + 3];
#pragma unroll
    for (int i = 0; i < 8; ++i) {
        int r = row0 + ty * 8 + i;
        if (r < nrows) {
            float4 v;
            v.x = acc[i][0] + b0;
            v.y = acc[i][1] + b1;
            v.z = acc[i][2] + b2;
            v.w = acc[i][3] + b3;
            ((float4*)out)[(size_t)r * 32 + tx] = v;
        }
    }
}

// ---------------------------------------------------------------------------
// BatchNorm statistics: stats[0..127]=sum, stats[128..255]=sumsq (pre-zeroed)
__global__ __launch_bounds__(256) void bn_stats(
    const float* __restrict__ z, float* __restrict__ stats, int nrows)
{
    int c = threadIdx.x & 127;
    int half = threadIdx.x >> 7;   // 0 or 1
    float s = 0.f, s2 = 0.f;
    for (int r = blockIdx.x * 2 + half; r < nrows; r += gridDim.x * 2) {
        float v = z[(size_t)r * HH + c];
        s += v;
        s2 += v * v;
    }
    __shared__ float sh[256];
    sh[threadIdx.x] = s;
    __syncthreads();
    if (half == 0) atomicAdd(&stats[c], s + sh[128 + c]);
    __syncthreads();
    sh[threadIdx.x] = s2;
    __syncthreads();
    if (half == 0) atomicAdd(&stats[128 + c], s2 + sh[128 + c]);
}

// scale[c] = rsqrt(var+eps)*gamma[c]; shift[c] = beta[c] - mean*scale[c]
__global__ void bn_finalize(
    const float* __restrict__ stats, const float* __restrict__ gamma,
    const float* __restrict__ beta, float* __restrict__ scale,
    float* __restrict__ shift)
{
    int c = threadIdx.x;   // 128 threads
    const float invN = 1.f / (float)NN;
    float m = stats[c] * invN;
    float var = stats[128 + c] * invN - m * m;
    float sc = rsqrtf(var + EPS_C) * gamma[c];
    scale[c] = sc;
    shift[c] = beta[c] - m * sc;
}

// ---------------------------------------------------------------------------
extern "C" void kernel_launch(void* const* d_in, const int* in_sizes, int n_in,
                              void* d_out, int out_size, void* d_ws, size_t ws_size,
                              hipStream_t stream)
{
    const float* x       = (const float*)d_in[0];
    const float* W_in    = (const float*)d_in[1];
    const float* b_in    = (const float*)d_in[2];
    const float* conv_W  = (const float*)d_in[3];
    const float* bn_g    = (const float*)d_in[4];
    const float* bn_b    = (const float*)d_in[5];
    const float* W_jk    = (const float*)d_in[6];
    const float* b_jk    = (const float*)d_in[7];
    const void*  srcp    = d_in[8];
    const void*  dstp    = d_in[9];

    // Workspace layout: 5*NH floats + 512 floats + 1 int  (~244 MiB)
    float* ws    = (float*)d_ws;
    float* x0    = ws;                        // [N,H] raw z0, residual
    float* msg   = ws + (size_t)NH;           // [N,H] scatter target
    float* zs0   = ws + 2 * (size_t)NH;       // raw z per layer; zs0 reused as JK out
    float* zs1   = ws + 3 * (size_t)NH;
    float* zs2   = ws + 4 * (size_t)NH;
    float* stats = ws + 5 * (size_t)NH;       // [256] sum/sumsq
    float* scale = stats + 256;               // [128]
    float* shift = scale + 128;               // [128]
    int*   flag  = (int*)(shift + 128);

    const int GEMM_GRID = (NN + TR - 1) / TR;     // 1563
    const int ZERO_GRID = (NH / 4 + 255) / 256;   // 12500

    detect_idx64<<<1, 1, 0, stream>>>((const int*)srcp, flag);

    // x0 = x @ W_in + b_in
    gemm128<<<GEMM_GRID, 256, 0, stream>>>(x, x, 1.f, 0.f, W_in, b_in,
                                           0.f, 1.f, x0, NN);

    const float* act = x0;          // activation fed to scatter
    const float* aff_sc = nullptr;  // fused BN scale/shift (null = identity)
    const float* aff_sh = nullptr;

    for (int i = 0; i < 5; ++i) {
        zero_k<<<ZERO_GRID, 256, 0, stream>>>((float4*)msg, NH / 4);
        scatter_add_k<<<EE / 4, 256, 0, stream>>>(act, srcp, dstp, flag,
                                                  aff_sc, aff_sh, msg);

        float bl = logf(THETA_C / (float)(i + 1) + 1.f);
        float* zraw = (i >= 3) ? (float*)d_out
                               : (zs0 + (size_t)i * NH);
        gemm128<<<GEMM_GRID, 256, 0, stream>>>(msg, x0, 1.f - ALPHA_C, ALPHA_C,
                                               conv_W + (size_t)i * HH * HH, nullptr,
                                               1.f - bl, bl, zraw, NN);
        if (i < 3) {
            zero_k<<<1, 256, 0, stream>>>((float4*)stats, 64);
            bn_stats<<<256, 256, 0, stream>>>(zraw, stats, NN);
            bn_finalize<<<1, 128, 0, stream>>>(stats, bn_g + (size_t)i * HH,
                                               bn_b + (size_t)i * HH, scale, shift);
            act = zraw;          // raw z, BN+ReLU fused into next scatter
            aff_sc = scale;
            aff_sh = shift;
        } else if (i == 3) {
            // JK: concat(zs0,zs1,zs2,d_out) @ W_jk + b_jk -> zs0 (alias-safe)
            gemm_jk<<<GEMM_GRID, 256, 0, stream>>>(zs0, zs1, zs2,
                                                   (const float*)d_out, W_jk, b_jk,
                                                   zs0, NN);
            act = zs0;
            aff_sc = nullptr;
            aff_sh = nullptr;
        }
        // i == 4: final output already in d_out
    }
}

// Round 3
// 2665.653 us; speedup vs baseline: 3.0656x; 3.0656x over previous
//
#include <hip/hip_runtime.h>
#include <hip/hip_bf16.h>
#include <cmath>
#include <cstddef>

// Problem constants (from reference)
#define NN 100000
#define HH 128
#define EE 1600000
#define NH (NN * HH)
#define ALPHA_C 0.1f
#define THETA_C 0.5f
#define EPS_C 1e-5f

constexpr int TR = 64;    // rows per GEMM block
constexpr int AST = 66;   // LDS A-tile stride (floats): 2-way max conflict, float2-aligned
constexpr int SCAN_B = 256;
constexpr int NBLK = (NN + SCAN_B - 1) / SCAN_B;   // 391 scan blocks

// ---------------------------------------------------------------------------
__global__ __launch_bounds__(256) void zero_int_k(int* __restrict__ p, int n) {
    int i = blockIdx.x * 256 + threadIdx.x;
    if (i < n) p[i] = 0;
}
__global__ __launch_bounds__(256) void zero_f4_k(float4* __restrict__ p, int n4) {
    int i = blockIdx.x * 256 + threadIdx.x;
    if (i < n4) p[i] = float4{0.f, 0.f, 0.f, 0.f};
}

// ---------------------------------------------------------------------------
// Index dtype detection: int64 (values < 2^31) -> every odd 32-bit word is 0.
__global__ void detect_idx64(const int* __restrict__ p, int* __restrict__ flag) {
    int any = 0;
    for (int i = 0; i < 64; ++i) any |= p[2 * i + 1];
    *flag = (any == 0) ? 1 : 0;
}

__device__ __forceinline__ int load_idx(const void* p, int e, int is64) {
    return is64 ? (int)((const long long*)p)[e] : ((const int*)p)[e];
}

// ---------------------------------------------------------------------------
// CSR build: histogram of dst
__global__ __launch_bounds__(256) void hist_k(
    const void* __restrict__ dstp, const int* __restrict__ flag,
    int* __restrict__ hist)
{
    int e = blockIdx.x * 256 + threadIdx.x;
    if (e >= EE) return;
    atomicAdd(&hist[load_idx(dstp, e, *flag)], 1);
}

// Block-local inclusive scan (256 elems/block) + per-block totals
__global__ __launch_bounds__(SCAN_B) void scan1_k(
    const int* __restrict__ hist, int* __restrict__ incl, int* __restrict__ bsum)
{
    __shared__ int sh[SCAN_B];
    int t = threadIdx.x;
    int i = blockIdx.x * SCAN_B + t;
    int v = (i < NN) ? hist[i] : 0;
    sh[t] = v;
    __syncthreads();
    for (int off = 1; off < SCAN_B; off <<= 1) {
        int x = (t >= off) ? sh[t - off] : 0;
        __syncthreads();
        sh[t] += x;
        __syncthreads();
    }
    if (i < NN) incl[i] = sh[t];
    if (t == SCAN_B - 1) bsum[blockIdx.x] = sh[t];
}

// Inclusive scan of the 391 block sums (single block, 512 threads)
__global__ __launch_bounds__(512) void scan2_k(int* __restrict__ bsum) {
    __shared__ int sh[512];
    int t = threadIdx.x;
    sh[t] = (t < NBLK) ? bsum[t] : 0;
    __syncthreads();
    for (int off = 1; off < 512; off <<= 1) {
        int x = (t >= off) ? sh[t - off] : 0;
        __syncthreads();
        sh[t] += x;
        __syncthreads();
    }
    if (t < NBLK) bsum[t] = sh[t];
}

// row_ptr[i] = exclusive prefix; cursor[i] = copy for fill; row_ptr[NN] = E
__global__ __launch_bounds__(SCAN_B) void scan3_k(
    const int* __restrict__ hist, const int* __restrict__ incl,
    const int* __restrict__ bsum, int* __restrict__ row_ptr,
    int* __restrict__ cursor)
{
    int b = blockIdx.x;
    int i = b * SCAN_B + threadIdx.x;
    if (i < NN) {
        int ex = incl[i] - hist[i] + (b > 0 ? bsum[b - 1] : 0);
        row_ptr[i] = ex;
        cursor[i] = ex;
    }
    if (i == 0) row_ptr[NN] = EE;
}

// Fill sorted source-index list (order within a bin is arbitrary; fp sum
// order differs from reference only at rounding level)
__global__ __launch_bounds__(256) void fill_k(
    const void* __restrict__ srcp, const void* __restrict__ dstp,
    const int* __restrict__ flag, int* __restrict__ cursor,
    int* __restrict__ sorted_src)
{
    int e = blockIdx.x * 256 + threadIdx.x;
    if (e >= EE) return;
    int is64 = *flag;
    int d = load_idx(dstp, e, is64);
    int pos = atomicAdd(&cursor[d], 1);
    sorted_src[pos] = load_idx(srcp, e, is64);
}

// ---------------------------------------------------------------------------
// CSR gather: msg[n] = sum over in-edges of (optional BN+ReLU of) z[src]
// One wave per node, float2 per lane (512B rows, coalesced).
__global__ __launch_bounds__(256) void gather_k(
    const float* __restrict__ z, const int* __restrict__ row_ptr,
    const int* __restrict__ sorted_src,
    const float* __restrict__ scale, const float* __restrict__ shift,
    float* __restrict__ msg)
{
    int node = blockIdx.x * 4 + (threadIdx.x >> 6);
    if (node >= NN) return;
    int lane = threadIdx.x & 63;
    int e0 = row_ptr[node], e1 = row_ptr[node + 1];
    float sc0 = 1.f, sc1 = 1.f, sh0 = 0.f, sh1 = 0.f;
    const bool bn = (scale != nullptr);
    if (bn) {
        int c = lane * 2;
        sc0 = scale[c]; sc1 = scale[c + 1];
        sh0 = shift[c]; sh1 = shift[c + 1];
    }
    float ax = 0.f, ay = 0.f;
    for (int e = e0; e < e1; ++e) {
        int s = sorted_src[e];
        float2 v = ((const float2*)(z + (size_t)s * HH))[lane];
        if (bn) {
            v.x = fmaxf(0.f, v.x * sc0 + sh0);
            v.y = fmaxf(0.f, v.y * sc1 + sh1);
        }
        ax += v.x; ay += v.y;
    }
    ((float2*)(msg + (size_t)node * HH))[lane] = float2{ax, ay};
}

// ---------------------------------------------------------------------------
// Generic 128-col GEMM block with fused GCNII epilogue.
//   A_eff[r][k] = cA*src0[r][k] + cB*src1[r][k]   (h = 0.9*msg + 0.1*x0)
//   out[r][c]   = wl*A_eff[r][c] + wm*(A_eff @ W)[r][c] + bias[c]
__global__ __launch_bounds__(256) void gemm128(
    const float* __restrict__ src0, const float* __restrict__ src1,
    float cA, float cB,
    const float* __restrict__ W, const float* __restrict__ bias,
    float wl, float wm, float* __restrict__ out, int nrows)
{
    __shared__ float As[HH * AST];   // A^T tile: [k][row], 128 x 66 -> 33.8 KB
    __shared__ float Ws[32 * HH];    // W chunk:  [k][c],    32 x 128 -> 16 KB

    const int t = threadIdx.x;
    const int tx = t & 31;           // cols 4*tx .. 4*tx+3
    const int ty = t >> 5;           // rows 8*ty .. 8*ty+7
    const int row0 = blockIdx.x * TR;

    const bool useB = (cB != 0.f);
    for (int idx = t; idx < TR * HH; idx += 256) {
        int r = idx >> 7;
        int k = idx & 127;
        float v = 0.f;
        if (row0 + r < nrows) {
            size_t g = (size_t)(row0 + r) * HH + k;
            v = cA * src0[g];
            if (useB) v += cB * src1[g];
        }
        As[k * AST + r] = v;
    }

    float acc[8][4];
#pragma unroll
    for (int i = 0; i < 8; ++i)
#pragma unroll
        for (int j = 0; j < 4; ++j) acc[i][j] = 0.f;

    for (int kc = 0; kc < 4; ++kc) {
        __syncthreads();
        for (int idx = t; idx < 32 * HH; idx += 256) {
            int k = idx >> 7, c = idx & 127;
            Ws[idx] = W[(size_t)(kc * 32 + k) * HH + c];
        }
        __syncthreads();
#pragma unroll
        for (int k = 0; k < 32; ++k) {
            const float* ap = &As[(kc * 32 + k) * AST + ty * 8];
            float2 a01 = *(const float2*)(ap);
            float2 a23 = *(const float2*)(ap + 2);
            float2 a45 = *(const float2*)(ap + 4);
            float2 a67 = *(const float2*)(ap + 6);
            float4 w = *(const float4*)(&Ws[k * HH + tx * 4]);
            float a[8] = {a01.x, a01.y, a23.x, a23.y, a45.x, a45.y, a67.x, a67.y};
#pragma unroll
            for (int i = 0; i < 8; ++i) {
                acc[i][0] += a[i] * w.x;
                acc[i][1] += a[i] * w.y;
                acc[i][2] += a[i] * w.z;
                acc[i][3] += a[i] * w.w;
            }
        }
    }

    float b0 = 0.f, b1 = 0.f, b2 = 0.f, b3 = 0.f;
    if (bias) {
        b0 = bias[tx * 4 + 0]; b1 = bias[tx * 4 + 1];
        b2 = bias[tx * 4 + 2]; b3 = bias[tx * 4 + 3];
    }
#pragma unroll
    for (int i = 0; i < 8; ++i) {
        int rl = ty * 8 + i;
        int r = row0 + rl;
        if (r < nrows) {
            float4 v;
            v.x = wl * As[(tx * 4 + 0) * AST + rl] + wm * acc[i][0] + b0;
            v.y = wl * As[(tx * 4 + 1) * AST + rl] + wm * acc[i][1] + b1;
            v.z = wl * As[(tx * 4 + 2) * AST + rl] + wm * acc[i][2] + b2;
            v.w = wl * As[(tx * 4 + 3) * AST + rl] + wm * acc[i][3] + b3;
            ((float4*)out)[(size_t)r * 32 + tx] = v;
        }
    }
}

// ---------------------------------------------------------------------------
// JumpingKnowledge GEMM: out = concat(z0..z3)[N,512] @ Wjk[512,128] + bjk
// out may alias z0 (each block reads its z0 rows before writing them).
__global__ __launch_bounds__(256) void gemm_jk(
    const float* __restrict__ z0, const float* __restrict__ z1,
    const float* __restrict__ z2, const float* __restrict__ z3,
    const float* __restrict__ Wjk, const float* __restrict__ bjk,
    float* __restrict__ out, int nrows)
{
    __shared__ float As[HH * AST];
    __shared__ float Ws[32 * HH];

    const int t = threadIdx.x;
    const int tx = t & 31;
    const int ty = t >> 5;
    const int row0 = blockIdx.x * TR;

    float acc[8][4];
#pragma unroll
    for (int i = 0; i < 8; ++i)
#pragma unroll
        for (int j = 0; j < 4; ++j) acc[i][j] = 0.f;

    const float* srcs[4] = {z0, z1, z2, z3};
    for (int j = 0; j < 4; ++j) {
        __syncthreads();
        const float* Z = srcs[j];
        for (int idx = t; idx < TR * HH; idx += 256) {
            int r = idx >> 7;
            int k = idx & 127;
            float v = 0.f;
            if (row0 + r < nrows) v = Z[(size_t)(row0 + r) * HH + k];
            As[k * AST + r] = v;
        }
        for (int kc = 0; kc < 4; ++kc) {
            __syncthreads();
            for (int idx = t; idx < 32 * HH; idx += 256) {
                int k = idx >> 7, c = idx & 127;
                Ws[idx] = Wjk[(size_t)(j * 128 + kc * 32 + k) * HH + c];
            }
            __syncthreads();
#pragma unroll
            for (int k = 0; k < 32; ++k) {
                const float* ap = &As[(kc * 32 + k) * AST + ty * 8];
                float2 a01 = *(const float2*)(ap);
                float2 a23 = *(const float2*)(ap + 2);
                float2 a45 = *(const float2*)(ap + 4);
                float2 a67 = *(const float2*)(ap + 6);
                float4 w = *(const float4*)(&Ws[k * HH + tx * 4]);
                float a[8] = {a01.x, a01.y, a23.x, a23.y, a45.x, a45.y, a67.x, a67.y};
#pragma unroll
                for (int i = 0; i < 8; ++i) {
                    acc[i][0] += a[i] * w.x;
                    acc[i][1] += a[i] * w.y;
                    acc[i][2] += a[i] * w.z;
                    acc[i][3] += a[i] * w.w;
                }
            }
        }
    }

    float b0 = bjk[tx * 4 + 0], b1 = bjk[tx * 4 + 1];
    float b2 = bjk[tx * 4 + 2], b3 = bjk[tx * 4 + 3];
#pragma unroll
    for (int i = 0; i < 8; ++i) {
        int r = row0 + ty * 8 + i;
        if (r < nrows) {
            float4 v;
            v.x = acc[i][0] + b0;
            v.y = acc[i][1] + b1;
            v.z = acc[i][2] + b2;
            v.w = acc[i][3] + b3;
            ((float4*)out)[(size_t)r * 32 + tx] = v;
        }
    }
}

// ---------------------------------------------------------------------------
// BatchNorm statistics: stats[0..127]=sum, stats[128..255]=sumsq (pre-zeroed)
__global__ __launch_bounds__(256) void bn_stats(
    const float* __restrict__ z, float* __restrict__ stats, int nrows)
{
    int c = threadIdx.x & 127;
    int half = threadIdx.x >> 7;
    float s = 0.f, s2 = 0.f;
    for (int r = blockIdx.x * 2 + half; r < nrows; r += gridDim.x * 2) {
        float v = z[(size_t)r * HH + c];
        s += v;
        s2 += v * v;
    }
    __shared__ float sh[256];
    sh[threadIdx.x] = s;
    __syncthreads();
    if (half == 0) atomicAdd(&stats[c], s + sh[128 + c]);
    __syncthreads();
    sh[threadIdx.x] = s2;
    __syncthreads();
    if (half == 0) atomicAdd(&stats[128 + c], s2 + sh[128 + c]);
}

// scale[c] = rsqrt(var+eps)*gamma[c]; shift[c] = beta[c] - mean*scale[c]
__global__ void bn_finalize(
    const float* __restrict__ stats, const float* __restrict__ gamma,
    const float* __restrict__ beta, float* __restrict__ scale,
    float* __restrict__ shift)
{
    int c = threadIdx.x;   // 128 threads
    const float invN = 1.f / (float)NN;
    float m = stats[c] * invN;
    float var = stats[128 + c] * invN - m * m;
    float sc = rsqrtf(var + EPS_C) * gamma[c];
    scale[c] = sc;
    shift[c] = beta[c] - m * sc;
}

// ---------------------------------------------------------------------------
extern "C" void kernel_launch(void* const* d_in, const int* in_sizes, int n_in,
                              void* d_out, int out_size, void* d_ws, size_t ws_size,
                              hipStream_t stream)
{
    const float* x       = (const float*)d_in[0];
    const float* W_in    = (const float*)d_in[1];
    const float* b_in    = (const float*)d_in[2];
    const float* conv_W  = (const float*)d_in[3];
    const float* bn_g    = (const float*)d_in[4];
    const float* bn_b    = (const float*)d_in[5];
    const float* W_jk    = (const float*)d_in[6];
    const float* b_jk    = (const float*)d_in[7];
    const void*  srcp    = d_in[8];
    const void*  dstp    = d_in[9];

    // Workspace: 5*NH floats (244 MiB) + CSR arrays (~8 MB) + stats
    float* ws    = (float*)d_ws;
    float* x0    = ws;                        // [N,H] raw z0, residual
    float* msg   = ws + (size_t)NH;           // [N,H] gather target
    float* zs0   = ws + 2 * (size_t)NH;       // raw z per layer; zs0 reused as JK out
    float* zs1   = ws + 3 * (size_t)NH;
    float* zs2   = ws + 4 * (size_t)NH;
    float* stats = ws + 5 * (size_t)NH;       // [256]
    float* scale = stats + 256;               // [128]
    float* shift = scale + 128;               // [128]
    int*   flag       = (int*)(shift + 128);
    int*   hist       = flag + 1;             // [NN]
    int*   incl       = hist + NN;            // [NN]
    int*   row_ptr    = incl + NN;            // [NN+1]
    int*   cursor     = row_ptr + NN + 1;     // [NN]
    int*   bsum       = cursor + NN;          // [NBLK]
    int*   sorted_src = bsum + NBLK + 1;      // [EE]

    const int GEMM_GRID = (NN + TR - 1) / TR;     // 1563
    const int EDGE_GRID = (EE + 255) / 256;       // 6250
    const int NODE_GRID = (NN + 3) / 4;           // 25000

    // ---- CSR build (once per launch) ----
    detect_idx64<<<1, 1, 0, stream>>>((const int*)srcp, flag);
    zero_int_k<<<(NN + 255) / 256, 256, 0, stream>>>(hist, NN);
    hist_k<<<EDGE_GRID, 256, 0, stream>>>(dstp, flag, hist);
    scan1_k<<<NBLK, SCAN_B, 0, stream>>>(hist, incl, bsum);
    scan2_k<<<1, 512, 0, stream>>>(bsum);
    scan3_k<<<NBLK, SCAN_B, 0, stream>>>(hist, incl, bsum, row_ptr, cursor);
    fill_k<<<EDGE_GRID, 256, 0, stream>>>(srcp, dstp, flag, cursor, sorted_src);

    // ---- x0 = x @ W_in + b_in ----
    gemm128<<<GEMM_GRID, 256, 0, stream>>>(x, x, 1.f, 0.f, W_in, b_in,
                                           0.f, 1.f, x0, NN);

    const float* act = x0;          // activation fed to gather
    const float* aff_sc = nullptr;  // fused BN scale/shift (null = identity)
    const float* aff_sh = nullptr;

    for (int i = 0; i < 5; ++i) {
        gather_k<<<NODE_GRID, 256, 0, stream>>>(act, row_ptr, sorted_src,
                                                aff_sc, aff_sh, msg);

        float bl = logf(THETA_C / (float)(i + 1) + 1.f);
        float* zraw = (i >= 3) ? (float*)d_out
                               : (zs0 + (size_t)i * NH);
        gemm128<<<GEMM_GRID, 256, 0, stream>>>(msg, x0, 1.f - ALPHA_C, ALPHA_C,
                                               conv_W + (size_t)i * HH * HH, nullptr,
                                               1.f - bl, bl, zraw, NN);
        if (i < 3) {
            zero_f4_k<<<1, 256, 0, stream>>>((float4*)stats, 64);
            bn_stats<<<256, 256, 0, stream>>>(zraw, stats, NN);
            bn_finalize<<<1, 128, 0, stream>>>(stats, bn_g + (size_t)i * HH,
                                               bn_b + (size_t)i * HH, scale, shift);
            act = zraw;          // BN+ReLU fused into next gather
            aff_sc = scale;
            aff_sh = shift;
        } else if (i == 3) {
            gemm_jk<<<GEMM_GRID, 256, 0, stream>>>(zs0, zs1, zs2,
                                                   (const float*)d_out, W_jk, b_jk,
                                                   zs0, NN);
            act = zs0;
            aff_sc = nullptr;
            aff_sh = nullptr;
        }
    }
}

// Round 4
// 1910.984 us; speedup vs baseline: 4.2762x; 1.3949x over previous
//
#include <hip/hip_runtime.h>
#include <hip/hip_bf16.h>
#include <cmath>
#include <cstddef>

// Problem constants (from reference)
#define NN 100000
#define HH 128
#define EE 1600000
#define NH (NN * HH)
#define ALPHA_C 0.1f
#define THETA_C 0.5f
#define EPS_C 1e-5f

constexpr int TR = 64;    // rows per GEMM block
constexpr int AST = 68;   // LDS A^T stride (floats): 16B-aligned rows, b128-clean
constexpr int SCAN_B = 256;
constexpr int NBLK = (NN + SCAN_B - 1) / SCAN_B;   // 391 scan blocks

// ---------------------------------------------------------------------------
__global__ __launch_bounds__(256) void zero_int_k(int* __restrict__ p, int n) {
    int i = blockIdx.x * 256 + threadIdx.x;
    if (i < n) p[i] = 0;
}
__global__ __launch_bounds__(256) void zero_f4_k(float4* __restrict__ p, int n4) {
    int i = blockIdx.x * 256 + threadIdx.x;
    if (i < n4) p[i] = float4{0.f, 0.f, 0.f, 0.f};
}

// ---------------------------------------------------------------------------
// Index dtype detection: int64 (values < 2^31) -> every odd 32-bit word is 0.
__global__ void detect_idx64(const int* __restrict__ p, int* __restrict__ flag) {
    int any = 0;
    for (int i = 0; i < 64; ++i) any |= p[2 * i + 1];
    *flag = (any == 0) ? 1 : 0;
}

__device__ __forceinline__ int load_idx(const void* p, int e, int is64) {
    return is64 ? (int)((const long long*)p)[e] : ((const int*)p)[e];
}

// ---------------------------------------------------------------------------
// CSR build: histogram of dst
__global__ __launch_bounds__(256) void hist_k(
    const void* __restrict__ dstp, const int* __restrict__ flag,
    int* __restrict__ hist)
{
    int e = blockIdx.x * 256 + threadIdx.x;
    if (e >= EE) return;
    atomicAdd(&hist[load_idx(dstp, e, *flag)], 1);
}

__global__ __launch_bounds__(SCAN_B) void scan1_k(
    const int* __restrict__ hist, int* __restrict__ incl, int* __restrict__ bsum)
{
    __shared__ int sh[SCAN_B];
    int t = threadIdx.x;
    int i = blockIdx.x * SCAN_B + t;
    int v = (i < NN) ? hist[i] : 0;
    sh[t] = v;
    __syncthreads();
    for (int off = 1; off < SCAN_B; off <<= 1) {
        int x = (t >= off) ? sh[t - off] : 0;
        __syncthreads();
        sh[t] += x;
        __syncthreads();
    }
    if (i < NN) incl[i] = sh[t];
    if (t == SCAN_B - 1) bsum[blockIdx.x] = sh[t];
}

__global__ __launch_bounds__(512) void scan2_k(int* __restrict__ bsum) {
    __shared__ int sh[512];
    int t = threadIdx.x;
    sh[t] = (t < NBLK) ? bsum[t] : 0;
    __syncthreads();
    for (int off = 1; off < 512; off <<= 1) {
        int x = (t >= off) ? sh[t - off] : 0;
        __syncthreads();
        sh[t] += x;
        __syncthreads();
    }
    if (t < NBLK) bsum[t] = sh[t];
}

__global__ __launch_bounds__(SCAN_B) void scan3_k(
    const int* __restrict__ hist, const int* __restrict__ incl,
    const int* __restrict__ bsum, int* __restrict__ row_ptr,
    int* __restrict__ cursor)
{
    int b = blockIdx.x;
    int i = b * SCAN_B + threadIdx.x;
    if (i < NN) {
        int ex = incl[i] - hist[i] + (b > 0 ? bsum[b - 1] : 0);
        row_ptr[i] = ex;
        cursor[i] = ex;
    }
    if (i == 0) row_ptr[NN] = EE;
}

__global__ __launch_bounds__(256) void fill_k(
    const void* __restrict__ srcp, const void* __restrict__ dstp,
    const int* __restrict__ flag, int* __restrict__ cursor,
    int* __restrict__ sorted_src)
{
    int e = blockIdx.x * 256 + threadIdx.x;
    if (e >= EE) return;
    int is64 = *flag;
    int d = load_idx(dstp, e, is64);
    int pos = atomicAdd(&cursor[d], 1);
    sorted_src[pos] = load_idx(srcp, e, is64);
}

// ---------------------------------------------------------------------------
// CSR gather: msg[n] = sum over in-edges of (optional BN+ReLU of) z[src]
__global__ __launch_bounds__(256) void gather_k(
    const float* __restrict__ z, const int* __restrict__ row_ptr,
    const int* __restrict__ sorted_src,
    const float* __restrict__ scale, const float* __restrict__ shift,
    float* __restrict__ msg)
{
    int node = blockIdx.x * 4 + (threadIdx.x >> 6);
    if (node >= NN) return;
    int lane = threadIdx.x & 63;
    int e0 = row_ptr[node], e1 = row_ptr[node + 1];
    float sc0 = 1.f, sc1 = 1.f, sh0 = 0.f, sh1 = 0.f;
    const bool bn = (scale != nullptr);
    if (bn) {
        int c = lane * 2;
        sc0 = scale[c]; sc1 = scale[c + 1];
        sh0 = shift[c]; sh1 = shift[c + 1];
    }
    float ax = 0.f, ay = 0.f;
    for (int e = e0; e < e1; ++e) {
        int s = sorted_src[e];
        float2 v = ((const float2*)(z + (size_t)s * HH))[lane];
        if (bn) {
            v.x = fmaxf(0.f, v.x * sc0 + sh0);
            v.y = fmaxf(0.f, v.y * sc1 + sh1);
        }
        ax += v.x; ay += v.y;
    }
    ((float2*)(msg + (size_t)node * HH))[lane] = float2{ax, ay};
}

// ---------------------------------------------------------------------------
// Weight prep: Wp[i] = W_in (i==0) else (1-bl_i)*I + bl_i*conv_W[i-1]
// (folds the GCNII residual combine into the weight matrix)
__global__ __launch_bounds__(256) void prep_w(
    const float* __restrict__ W_in, const float* __restrict__ conv_W,
    float* __restrict__ Wp)
{
    int i = blockIdx.y;                          // 0..5
    int idx = blockIdx.x * 256 + threadIdx.x;    // 0..16383
    float v;
    if (i == 0) {
        v = W_in[idx];
    } else {
        float bl = logf(THETA_C / (float)i + 1.f);
        int k = idx >> 7, c = idx & 127;
        v = bl * conv_W[(size_t)(i - 1) * 16384 + idx] + ((k == c) ? (1.f - bl) : 0.f);
    }
    Wp[(size_t)i * 16384 + idx] = v;
}

// ---------------------------------------------------------------------------
// 128-col GEMM, residual pre-folded into Wp.
//   A[r][k] = cA*src0[r][k] + cB*src1[r][k];  out = A @ Wp (+ bias)
// LDS: only A^T (34.8 KB -> 4 blocks/CU). W read from global (L2-hot, 64 KB).
// K-loop has NO barriers -> compiler free to pipeline all 128 iterations.
__global__ __launch_bounds__(256, 4) void gemm128(
    const float* __restrict__ src0, const float* __restrict__ src1,
    float cA, float cB, const float* __restrict__ Wp,
    const float* __restrict__ bias, float* __restrict__ out, int nrows)
{
    __shared__ float As[HH * AST];   // A^T [k][r], 128 x 68 floats
    const int t = threadIdx.x;
    const int tx = t & 31;           // output cols 4*tx..4*tx+3
    const int ty = t >> 5;           // rows 8*ty..8*ty+7
    const int lane = t & 63, w = t >> 6;
    const int row0 = blockIdx.x * TR;
    const bool useB = (cB != 0.f);

    // Stage A^T: wave-iter covers 16 rows x 4 k4-groups (64B/row segments,
    // LDS write banks = (16*(lane>>4&1) + (lane&15) + 4j) % 32 -> <=2-way)
#pragma unroll
    for (int i = 0; i < 8; ++i) {
        int r = (i & 3) * 16 + (lane & 15);
        int k4 = ((i >> 2) * 4 + w) * 4 + (lane >> 4);
        float4 v = {0.f, 0.f, 0.f, 0.f};
        if (row0 + r < nrows) {
            float4 a = ((const float4*)(src0 + (size_t)(row0 + r) * HH))[k4];
            if (useB) {
                float4 b = ((const float4*)(src1 + (size_t)(row0 + r) * HH))[k4];
                v.x = cA * a.x + cB * b.x; v.y = cA * a.y + cB * b.y;
                v.z = cA * a.z + cB * b.z; v.w = cA * a.w + cB * b.w;
            } else {
                v.x = cA * a.x; v.y = cA * a.y; v.z = cA * a.z; v.w = cA * a.w;
            }
        }
        int k = k4 * 4;
        As[(k + 0) * AST + r] = v.x;
        As[(k + 1) * AST + r] = v.y;
        As[(k + 2) * AST + r] = v.z;
        As[(k + 3) * AST + r] = v.w;
    }
    __syncthreads();

    float acc[8][4];
#pragma unroll
    for (int ii = 0; ii < 8; ++ii)
#pragma unroll
        for (int j = 0; j < 4; ++j) acc[ii][j] = 0.f;

    for (int k0 = 0; k0 < HH; k0 += 8) {
#pragma unroll
        for (int kk = 0; kk < 8; ++kk) {
            int k = k0 + kk;
            float4 wv = ((const float4*)(Wp + (size_t)k * HH))[tx];
            const float* ap = &As[k * AST + ty * 8];
            float4 a0 = *(const float4*)ap;
            float4 a1 = *(const float4*)(ap + 4);
            float a[8] = {a0.x, a0.y, a0.z, a0.w, a1.x, a1.y, a1.z, a1.w};
#pragma unroll
            for (int ii = 0; ii < 8; ++ii) {
                acc[ii][0] += a[ii] * wv.x;
                acc[ii][1] += a[ii] * wv.y;
                acc[ii][2] += a[ii] * wv.z;
                acc[ii][3] += a[ii] * wv.w;
            }
        }
    }

    float4 b4 = {0.f, 0.f, 0.f, 0.f};
    if (bias) b4 = ((const float4*)bias)[tx];
#pragma unroll
    for (int ii = 0; ii < 8; ++ii) {
        int r = row0 + ty * 8 + ii;
        if (r < nrows) {
            float4 v = {acc[ii][0] + b4.x, acc[ii][1] + b4.y,
                        acc[ii][2] + b4.z, acc[ii][3] + b4.w};
            ((float4*)out)[(size_t)r * 32 + tx] = v;
        }
    }
}

// ---------------------------------------------------------------------------
// JumpingKnowledge GEMM: out = concat(z0..z3)[N,512] @ Wjk[512,128] + bjk
// Same structure; 4 staged sources, K=128 each. out may alias z0 (each block
// reads only its own rows of each source, before its writes).
__global__ __launch_bounds__(256, 4) void gemm_jk(
    const float* __restrict__ z0, const float* __restrict__ z1,
    const float* __restrict__ z2, const float* __restrict__ z3,
    const float* __restrict__ Wjk, const float* __restrict__ bjk,
    float* __restrict__ out, int nrows)
{
    __shared__ float As[HH * AST];
    const int t = threadIdx.x;
    const int tx = t & 31;
    const int ty = t >> 5;
    const int lane = t & 63, w = t >> 6;
    const int row0 = blockIdx.x * TR;

    float acc[8][4];
#pragma unroll
    for (int ii = 0; ii < 8; ++ii)
#pragma unroll
        for (int j = 0; j < 4; ++j) acc[ii][j] = 0.f;

    const float* srcs[4] = {z0, z1, z2, z3};
    for (int j = 0; j < 4; ++j) {
        if (j) __syncthreads();   // previous source's reads done
        const float* Z = srcs[j];
#pragma unroll
        for (int i = 0; i < 8; ++i) {
            int r = (i & 3) * 16 + (lane & 15);
            int k4 = ((i >> 2) * 4 + w) * 4 + (lane >> 4);
            float4 v = {0.f, 0.f, 0.f, 0.f};
            if (row0 + r < nrows)
                v = ((const float4*)(Z + (size_t)(row0 + r) * HH))[k4];
            int k = k4 * 4;
            As[(k + 0) * AST + r] = v.x;
            As[(k + 1) * AST + r] = v.y;
            As[(k + 2) * AST + r] = v.z;
            As[(k + 3) * AST + r] = v.w;
        }
        __syncthreads();

        const float* Wj = Wjk + (size_t)j * 128 * HH;
        for (int k0 = 0; k0 < HH; k0 += 8) {
#pragma unroll
            for (int kk = 0; kk < 8; ++kk) {
                int k = k0 + kk;
                float4 wv = ((const float4*)(Wj + (size_t)k * HH))[tx];
                const float* ap = &As[k * AST + ty * 8];
                float4 a0 = *(const float4*)ap;
                float4 a1 = *(const float4*)(ap + 4);
                float a[8] = {a0.x, a0.y, a0.z, a0.w, a1.x, a1.y, a1.z, a1.w};
#pragma unroll
                for (int ii = 0; ii < 8; ++ii) {
                    acc[ii][0] += a[ii] * wv.x;
                    acc[ii][1] += a[ii] * wv.y;
                    acc[ii][2] += a[ii] * wv.z;
                    acc[ii][3] += a[ii] * wv.w;
                }
            }
        }
    }

    float4 b4 = ((const float4*)bjk)[tx];
#pragma unroll
    for (int ii = 0; ii < 8; ++ii) {
        int r = row0 + ty * 8 + ii;
        if (r < nrows) {
            float4 v = {acc[ii][0] + b4.x, acc[ii][1] + b4.y,
                        acc[ii][2] + b4.z, acc[ii][3] + b4.w};
            ((float4*)out)[(size_t)r * 32 + tx] = v;
        }
    }
}

// ---------------------------------------------------------------------------
// BatchNorm statistics: stats[0..127]=sum, stats[128..255]=sumsq (pre-zeroed)
__global__ __launch_bounds__(256) void bn_stats(
    const float* __restrict__ z, float* __restrict__ stats, int nrows)
{
    int c = threadIdx.x & 127;
    int half = threadIdx.x >> 7;
    float s = 0.f, s2 = 0.f;
    for (int r = blockIdx.x * 2 + half; r < nrows; r += gridDim.x * 2) {
        float v = z[(size_t)r * HH + c];
        s += v;
        s2 += v * v;
    }
    __shared__ float sh[256];
    sh[threadIdx.x] = s;
    __syncthreads();
    if (half == 0) atomicAdd(&stats[c], s + sh[128 + c]);
    __syncthreads();
    sh[threadIdx.x] = s2;
    __syncthreads();
    if (half == 0) atomicAdd(&stats[128 + c], s2 + sh[128 + c]);
}

__global__ void bn_finalize(
    const float* __restrict__ stats, const float* __restrict__ gamma,
    const float* __restrict__ beta, float* __restrict__ scale,
    float* __restrict__ shift)
{
    int c = threadIdx.x;   // 128 threads
    const float invN = 1.f / (float)NN;
    float m = stats[c] * invN;
    float var = stats[128 + c] * invN - m * m;
    float sc = rsqrtf(var + EPS_C) * gamma[c];
    scale[c] = sc;
    shift[c] = beta[c] - m * sc;
}

// ---------------------------------------------------------------------------
extern "C" void kernel_launch(void* const* d_in, const int* in_sizes, int n_in,
                              void* d_out, int out_size, void* d_ws, size_t ws_size,
                              hipStream_t stream)
{
    const float* x       = (const float*)d_in[0];
    const float* W_in    = (const float*)d_in[1];
    const float* b_in    = (const float*)d_in[2];
    const float* conv_W  = (const float*)d_in[3];
    const float* bn_g    = (const float*)d_in[4];
    const float* bn_b    = (const float*)d_in[5];
    const float* W_jk    = (const float*)d_in[6];
    const float* b_jk    = (const float*)d_in[7];
    const void*  srcp    = d_in[8];
    const void*  dstp    = d_in[9];

    // Workspace: 5*NH floats (244 MiB) + stats + CSR (~7.3 MB) + Wp (384 KB)
    float* ws    = (float*)d_ws;
    float* x0    = ws;                        // [N,H] z0, residual
    float* msg   = ws + (size_t)NH;           // [N,H] gather target
    float* zs0   = ws + 2 * (size_t)NH;       // z per layer; zs0 reused as JK out
    float* zs1   = ws + 3 * (size_t)NH;
    float* zs2   = ws + 4 * (size_t)NH;
    float* stats = ws + 5 * (size_t)NH;       // [256]
    float* scale = stats + 256;               // [128]
    float* shift = scale + 128;               // [128]
    int*   flag       = (int*)(shift + 128);
    int*   hist       = flag + 1;             // [NN]
    int*   incl       = hist + NN;            // [NN]
    int*   row_ptr    = incl + NN;            // [NN+1]
    int*   cursor     = row_ptr + NN + 1;     // [NN]
    int*   bsum       = cursor + NN;          // [NBLK]
    int*   sorted_src = bsum + NBLK + 1;      // [EE]
    float* Wp         = (float*)(sorted_src + EE);  // [6][128][128]

    const int GEMM_GRID = (NN + TR - 1) / TR;     // 1563
    const int EDGE_GRID = (EE + 255) / 256;       // 6250
    const int NODE_GRID = (NN + 3) / 4;           // 25000

    // ---- CSR build + weight prep (once per launch) ----
    detect_idx64<<<1, 1, 0, stream>>>((const int*)srcp, flag);
    zero_int_k<<<(NN + 255) / 256, 256, 0, stream>>>(hist, NN);
    hist_k<<<EDGE_GRID, 256, 0, stream>>>(dstp, flag, hist);
    scan1_k<<<NBLK, SCAN_B, 0, stream>>>(hist, incl, bsum);
    scan2_k<<<1, 512, 0, stream>>>(bsum);
    scan3_k<<<NBLK, SCAN_B, 0, stream>>>(hist, incl, bsum, row_ptr, cursor);
    fill_k<<<EDGE_GRID, 256, 0, stream>>>(srcp, dstp, flag, cursor, sorted_src);
    prep_w<<<dim3(64, 6), 256, 0, stream>>>(W_in, conv_W, Wp);

    // ---- x0 = x @ W_in + b_in ----
    gemm128<<<GEMM_GRID, 256, 0, stream>>>(x, x, 1.f, 0.f, Wp, b_in, x0, NN);

    const float* act = x0;
    const float* aff_sc = nullptr;
    const float* aff_sh = nullptr;

    for (int i = 0; i < 5; ++i) {
        gather_k<<<NODE_GRID, 256, 0, stream>>>(act, row_ptr, sorted_src,
                                                aff_sc, aff_sh, msg);

        float* zraw = (i >= 3) ? (float*)d_out : (zs0 + (size_t)i * NH);
        gemm128<<<GEMM_GRID, 256, 0, stream>>>(msg, x0, 1.f - ALPHA_C, ALPHA_C,
                                               Wp + (size_t)(i + 1) * 16384,
                                               nullptr, zraw, NN);
        if (i < 3) {
            zero_f4_k<<<1, 256, 0, stream>>>((float4*)stats, 64);
            bn_stats<<<256, 256, 0, stream>>>(zraw, stats, NN);
            bn_finalize<<<1, 128, 0, stream>>>(stats, bn_g + (size_t)i * HH,
                                               bn_b + (size_t)i * HH, scale, shift);
            act = zraw;          // BN+ReLU fused into next gather
            aff_sc = scale;
            aff_sh = shift;
        } else if (i == 3) {
            gemm_jk<<<GEMM_GRID, 256, 0, stream>>>(zs0, zs1, zs2,
                                                   (const float*)d_out, W_jk, b_jk,
                                                   zs0, NN);
            act = zs0;
            aff_sc = nullptr;
            aff_sh = nullptr;
        }
    }
}